// Round 5
// baseline (610.188 us; speedup 1.0000x reference)
//
#include <hip/hip_runtime.h>
#include <math.h>

#define IN_CH 768
#define OUT_CH 48
#define NB 32
#define HW 3136      // 56*56
#define HW4 784      // HW/4
#define NROWS (NB * IN_CH)     // 24576
#define POOL_GRID (NROWS / 4)  // 6144 blocks, wave-per-row (4 waves/block)

// clang-native float4 (HIP's float4 is a class; nontemporal builtin needs this)
typedef float f32x4 __attribute__((ext_vector_type(4)));

// ---------------- Kernel 1: fused global avg+max pool, one wave per row ----------------
__global__ __launch_bounds__(256) void pool_kernel(const float* __restrict__ in,
                                                   float* __restrict__ avg,
                                                   float* __restrict__ mx) {
    const int lane = threadIdx.x & 63;
    const int wv   = threadIdx.x >> 6;
    const int row  = blockIdx.x * 4 + wv;
    const f32x4* p = (const f32x4*)(in + (size_t)row * HW);
    float s = 0.f;
    float m = -INFINITY;
    for (int i = lane; i < HW4; i += 64) {
        f32x4 v = p[i];
        s += (v.x + v.y) + (v.z + v.w);
        m = fmaxf(m, fmaxf(fmaxf(v.x, v.y), fmaxf(v.z, v.w)));
    }
    for (int off = 32; off; off >>= 1) {
        s += __shfl_down(s, off);
        m = fmaxf(m, __shfl_down(m, off));
    }
    if (lane == 0) {
        avg[row] = s * (1.0f / (float)HW);
        mx[row]  = m;
    }
}

// ---------------- Kernel 2: tiny shared MLP + sigmoid -> gate ----------------
// gate[b,c] = sigmoid( (w2 @ (relu(w1@avg_b) + relu(w1@mx_b)))[c] )   (layer2 linear)
__global__ __launch_bounds__(256) void mlp_kernel(const float* __restrict__ avg,
                                                  const float* __restrict__ mx,
                                                  const float* __restrict__ w1,  // [48,768]
                                                  const float* __restrict__ w2,  // [768,48]
                                                  float* __restrict__ gate) {    // [B*768]
    const int b = blockIdx.x;
    __shared__ float sa[IN_CH], sx[IN_CH], hsum[OUT_CH];
    for (int c = threadIdx.x; c < IN_CH; c += 256) {
        sa[c] = avg[b * IN_CH + c];
        sx[c] = mx[b * IN_CH + c];
    }
    __syncthreads();
    const int lane = threadIdx.x & 63, wv = threadIdx.x >> 6;
    for (int o = wv; o < OUT_CH; o += 4) {
        const float* wrow = w1 + o * IN_CH;
        float pa = 0.f, px = 0.f;
        for (int c = lane; c < IN_CH; c += 64) {
            float w = wrow[c];
            pa += w * sa[c];
            px += w * sx[c];
        }
        for (int off = 32; off; off >>= 1) {
            pa += __shfl_down(pa, off);
            px += __shfl_down(px, off);
        }
        if (lane == 0) hsum[o] = fmaxf(pa, 0.f) + fmaxf(px, 0.f);
    }
    __syncthreads();
    for (int c = threadIdx.x; c < IN_CH; c += 256) {
        const float* wrow = w2 + c * OUT_CH;  // 48 consecutive floats
        float acc = 0.f;
#pragma unroll
        for (int o = 0; o < OUT_CH; ++o) acc += wrow[o] * hsum[o];
        gate[b * IN_CH + c] = 1.0f / (1.0f + expf(-acc));
    }
}

// ---------------- Kernel 3: scale, one wave per row, global reverse order ----------------
// Pool streamed rows 0..NROWS-1; L3 (256 MB) holds the tail of the 308 MB input.
// Reading rows in reverse hits the freshest cached data first. Output stores are
// non-temporal so the write stream doesn't evict input from L2/L3.
__global__ __launch_bounds__(256) void scale_kernel(const float* __restrict__ in,
                                                    const float* __restrict__ gate,
                                                    float* __restrict__ out) {
    const int lane = threadIdx.x & 63;
    const int wv   = threadIdx.x >> 6;
    const int row  = NROWS - 1 - (blockIdx.x * 4 + wv);
    const float g = gate[row];
    const f32x4* p = (const f32x4*)(in + (size_t)row * HW);
    f32x4* q = (f32x4*)(out + (size_t)row * HW);
    for (int i = lane; i < HW4; i += 64) {
        f32x4 v = p[i];
        v *= g;
        __builtin_nontemporal_store(v, q + i);
    }
}

extern "C" void kernel_launch(void* const* d_in, const int* in_sizes, int n_in,
                              void* d_out, int out_size, void* d_ws, size_t ws_size,
                              hipStream_t stream) {
    const float* in = (const float*)d_in[0];
    const float* w1 = (const float*)d_in[1];
    const float* w2 = (const float*)d_in[2];
    float* out = (float*)d_out;

    float* avg  = (float*)d_ws;            // [24576]
    float* mx   = avg + NROWS;             // [24576]
    float* gate = mx + NROWS;              // [24576]

    pool_kernel<<<POOL_GRID, 256, 0, stream>>>(in, avg, mx);
    mlp_kernel<<<NB, 256, 0, stream>>>(avg, mx, w1, w2, gate);
    scale_kernel<<<POOL_GRID, 256, 0, stream>>>(in, gate, out);
}